// Round 7
// baseline (318.142 us; speedup 1.0000x reference)
//
#include <hip/hip_runtime.h>

// PillarMotionNet voxelization for MI355X.
// Dense key space: 4 * 400 * 400 * 5 = 3.2M keys; 2M points.
//
// Measured walls:
//  - ATOMICS (device-scope RMW) run ~21 G/s, payload/locality-invariant —
//    they bypass L2 write-combining. PLAIN stores, even scattered 8B, DO
//    combine in L2 (R12: coalescing bin's scattered record writes was a
//    no-op, 265->259; R6: nt stores defeat combining -> plain stores only).
//  - R7: out gather: 2M random 8B gathers from 25.6MB pk ~= 103MB HBM fetch,
//    gather-CONCURRENCY-bound (3.3TB/s, VALUBusy <5%), ~2x from BW floor.
//  - R8: cooperative fusion REGRESSION: grid.sync at 1.5 blk/CU + 128B-stride
//    LDS reads (2.45M bank-conflict cycles). 8B-stride LDS reads are free.
//  - R9: __launch_bounds__(256,4) forced a 64-VGPR cap -> ~128B/thread spill
//    (FETCH +32MB). The 8pt structure itself was not the problem; the cap
//    was. This round: 8pt WITHOUT launch_bounds.
//  - R10: static LDS must stay <= 65,536B per workgroup.
//
// Pipeline (4 dispatches):
//  memset(gcnt+done, 2KB)
//  bin_kernel     1024thr x 4pt: nt-load 48MB; LDS hist; block scan; 1 global
//                 atomic per (block,bucket); LDS counting sort; linear write.
//  bucket_accum   16MB read; LDS accumulate; ballot present-mask; popcount
//                 scan -> LOCAL ranks; write pk dense FINAL-PACKED + gmask +
//                 bcnt (release atomic). LAST block (done counter) computes
//                 gbase[401] prefix + nu + grid-size (replaces scan_bcnt).
//  out_fused      unq-role (400 blks: decode gmask -> unq rows) + pad-role
//                 (128 blks: rows >= nu get -1) + out-role (8pt/thread:
//                 12 nt loads up front, 8 gathers + 8 gbase loads issued
//                 back-to-back, then two 4-pt feature halves).
//
// Record: [0:21] key  [22:34] qdx (*4096)  [35:47] qdy  [48:63] qdz (*32768)
// Accumulator (LDS): [0:17] sum qdx [18:35] sum qdy [36:56] sum qdz [57:63] cnt
// pk packed: [0:13] mqx  [14:27] mqy  [28:41] mqz  [42:54] local rank
// Absent pk slots hold 0; never read (every gathered key is present).
// recs (18MB) aliases d_out's feat region (accum consumes before out writes).

#define NKEYS 3200000
#define GX 400
#define GY 400
#define NT 5

#define NBUCK 400
#define TILE 8000        // keys per bucket; NBUCK * TILE == NKEYS
#define RCAP 5632        // records per bucket: mean 5000, sd ~71 (+8.9 sigma)
#define NWORDS 128       // gmask stride (64-bit words per bucket)
#define MWORDS 125       // words actually covering slots [0,8000)
#define NPADBLK 128
#define BINPTS 4096      // points staged per bin block (1024 thr x 4)

typedef __attribute__((ext_vector_type(4))) float vf4;
typedef unsigned long long u64;

__device__ __forceinline__ void make_rec(float b, float x, float y, float z,
                                         float t, int* bkt, u64* rec) {
    float u = (x + 50.0f) * 4.0f;
    float v = (y + 50.0f) * 4.0f;
    int cx = (int)u;
    int cy = (int)v;
    float dx = u - (float)cx;              // exact, in [0,1)
    float dy = v - (float)cy;
    float dz = (z + 5.0f) * 0.125f;        // [0,1)
    int key = (((int)b * GX + cx) * GY + cy) * NT + (int)t;
    u64 qdx = (u64)(unsigned int)rintf(dx * 4096.0f);    // <= 4096, 13 bits
    u64 qdy = (u64)(unsigned int)rintf(dy * 4096.0f);
    u64 qdz = (u64)(unsigned int)rintf(dz * 32768.0f);   // <= 32768, 16 bits
    *bkt = key / TILE;
    *rec = (u64)(unsigned int)key | (qdx << 22) | (qdy << 35) | (qdz << 48);
}

// Block-local counting sort -> coalesced per-bucket run writes.
// LDS: 32768 (lrec) + 3*1600 + 64 + 8 = 37,640 B.
__global__ __launch_bounds__(1024) void bin_kernel(const vf4* __restrict__ pts4,
                                                   int n, int* __restrict__ gcnt,
                                                   u64* __restrict__ recs) {
    __shared__ u64 lrec[BINPTS];
    __shared__ int hist[NBUCK];
    __shared__ int pref[NBUCK];
    __shared__ int dlt[NBUCK];
    __shared__ int wsum[16];
    __shared__ int sTotal;
    int tid = threadIdx.x;
    int lane = tid & 63;
    int wv = tid >> 6;              // 0..15
    if (tid < NBUCK) hist[tid] = 0;
    __syncthreads();

    int i = blockIdx.x * 1024 + tid;
    int p0 = i * 4;
    int bkt[4];
    u64 rec[4];
    int lrk[4];
    int nv = 0;
    if (p0 + 3 < n) {
        vf4 a0 = __builtin_nontemporal_load(pts4 + (size_t)6 * i + 0);
        vf4 a1 = __builtin_nontemporal_load(pts4 + (size_t)6 * i + 1);
        vf4 a2 = __builtin_nontemporal_load(pts4 + (size_t)6 * i + 2);
        vf4 a3 = __builtin_nontemporal_load(pts4 + (size_t)6 * i + 3);
        vf4 a4 = __builtin_nontemporal_load(pts4 + (size_t)6 * i + 4);
        vf4 a5 = __builtin_nontemporal_load(pts4 + (size_t)6 * i + 5);
        make_rec(a0.x, a0.y, a0.z, a0.w, a1.y, &bkt[0], &rec[0]);
        make_rec(a1.z, a1.w, a2.x, a2.y, a2.w, &bkt[1], &rec[1]);
        make_rec(a3.x, a3.y, a3.z, a3.w, a4.y, &bkt[2], &rec[2]);
        make_rec(a4.z, a4.w, a5.x, a5.y, a5.w, &bkt[3], &rec[3]);
        nv = 4;
    } else if (p0 < n) {
        const float* p = (const float*)pts4;
#pragma unroll
        for (int k = 0; k < 4; ++k) {
            int j = p0 + k;
            if (j < n) {
                make_rec(p[6 * j], p[6 * j + 1], p[6 * j + 2], p[6 * j + 3],
                         p[6 * j + 5], &bkt[k], &rec[k]);
                nv = k + 1;
            }
        }
    }
#pragma unroll
    for (int k = 0; k < 4; ++k)
        if (k < nv) lrk[k] = atomicAdd(&hist[bkt[k]], 1);
    __syncthreads();

    // block scan of the 400 bucket counts (tid >= 400 contribute 0)
    int v = (tid < NBUCK) ? hist[tid] : 0;
    int x = v;
#pragma unroll
    for (int off = 1; off < 64; off <<= 1) {
        int y = __shfl_up(x, off, 64);
        if (lane >= off) x += y;
    }
    if (lane == 63) wsum[wv] = x;
    __syncthreads();
    if (wv == 0) {
        int w = (lane < 16) ? wsum[lane] : 0;
#pragma unroll
        for (int off = 1; off < 16; off <<= 1) {
            int y = __shfl_up(w, off, 64);
            if (lane >= off) w += y;
        }
        if (lane < 16) wsum[lane] = w;   // inclusive wave prefix
    }
    __syncthreads();
    int waveExcl = (wv == 0) ? 0 : wsum[wv - 1];
    int excl = waveExcl + x - v;
    if (tid < NBUCK) {
        pref[tid] = excl;
        int gb = atomicAdd(&gcnt[tid], v);   // reserve this block's run
        dlt[tid] = gb - excl;                // slot -> in-bucket position
    }
    if (tid == 1023) sTotal = waveExcl + x;  // total records in block
    __syncthreads();

    // scatter into LDS, sorted by bucket (slot order == bucket-run order)
#pragma unroll
    for (int k = 0; k < 4; ++k)
        if (k < nv) lrec[pref[bkt[k]] + lrk[k]] = rec[k];
    __syncthreads();

    // linear write-out: consecutive threads -> consecutive slots -> runs
    int tot = sTotal;
#pragma unroll
    for (int j = 0; j < 4; ++j) {
        int slot = tid + j * 1024;
        if (slot < tot) {
            u64 rc = lrec[slot];
            int key = (int)(rc & 0x3FFFFFULL);
            int bk = key / TILE;             // magic-mul division
            int gpos = dlt[bk] + slot;
            if (gpos < RCAP)                 // statistically impossible guard
                recs[(size_t)bk * RCAP + gpos] = rc;
        }
    }
}

// One block per bucket. LDS accumulate; ballot present-mask; popcount scan ->
// local ranks; write pk dense final-packed + gmask + bcnt. LAST block (done
// counter) computes the global prefix gbase[401] + nu + grid-size.
// Static LDS: 64000 + 1000 + 500 + 4 = 65,504 B (limit 65,536).
__global__ __launch_bounds__(1024) void bucket_accum_kernel(
        const u64* __restrict__ recs, const int* __restrict__ gcnt,
        u64* __restrict__ pk, int* __restrict__ bcnt, u64* __restrict__ gmask,
        int* __restrict__ done, int* __restrict__ gbase,
        float* __restrict__ gs) {
    __shared__ u64 tbl[TILE];       // 64,000 B
    __shared__ u64 msk[MWORDS];     // present bitmask, words 0..124
    __shared__ int wrank[MWORDS];   // excl rank at word start; reused by scan
    __shared__ int w0tot;           // reused as isLast flag
    int tid = threadIdx.x;
    int lane = tid & 63;
    int wv = tid >> 6;              // 0..15
    int b = blockIdx.x;
    for (int s = tid; s < TILE; s += 1024) tbl[s] = 0;
    __syncthreads();
    int cnt = gcnt[b];
    if (cnt > RCAP) cnt = RCAP;
    const u64* rp = recs + (size_t)b * RCAP;
    int base = b * TILE;
    for (int r = tid; r < cnt; r += 1024) {
        u64 v = __builtin_nontemporal_load(rp + r);
        int slot = (int)(v & 0x3FFFFFULL) - base;
        u64 qdx = (v >> 22) & 0x1FFFULL;
        u64 qdy = (v >> 35) & 0x1FFFULL;
        u64 qdz = v >> 48;
        atomicAdd(&tbl[slot], qdx | (qdy << 18) | (qdz << 36) | (1ULL << 57));
    }
    __syncthreads();
    // present-mask via ballot; lanes of a wave cover 64 consecutive slots.
#pragma unroll
    for (int j = 0; j < 8; ++j) {
        int s = tid + j * 1024;
        bool p = (s < TILE) && (tbl[s] != 0ULL);
        u64 bal = __ballot(p);
        int w = s >> 6;                     // = j*16 + wave
        if (lane == 0 && w < MWORDS) msk[w] = bal;
    }
    __syncthreads();
    // exclusive prefix over 125 word popcounts (threads 0..124)
    int pc = 0, xi = 0;
    if (tid < MWORDS) {
        pc = __popcll(msk[tid]);
        xi = pc;
#pragma unroll
        for (int off = 1; off < 64; off <<= 1) {
            int y = __shfl_up(xi, off, 64);
            if (lane >= off) xi += y;
        }
        if (tid == 63) w0tot = xi;
    }
    __syncthreads();
    if (tid < MWORDS) {
        int add = (tid >= 64) ? w0tot : 0;
        wrank[tid] = xi - pc + add;
        if (tid == MWORDS - 1)              // bucket unique count, release
            __hip_atomic_store(&bcnt[b], xi + add, __ATOMIC_RELEASE,
                               __HIP_MEMORY_SCOPE_AGENT);
        gmask[(size_t)b * NWORDS + tid] = msk[tid];
    } else if (tid < NWORDS) {
        gmask[(size_t)b * NWORDS + tid] = 0ULL;      // structural zeros
    }
    __syncthreads();
    // final-packed pk write; strided tile reads (conflict-free); full lines.
#pragma unroll
    for (int j = 0; j < 8; ++j) {
        int s = tid + j * 1024;
        if (s < TILE) {
            u64 v = tbl[s];
            u64 outv = 0ULL;
            if (v) {
                float cntf = (float)(unsigned int)(v >> 57);
                float rcp = 16383.0f / cntf;
                unsigned int sx = (unsigned int)(v & 0x3FFFFULL);
                unsigned int sy = (unsigned int)((v >> 18) & 0x3FFFFULL);
                unsigned int sz = (unsigned int)((v >> 36) & 0x1FFFFFULL);
                u64 mqx = (u64)(unsigned int)rintf((float)sx * rcp * 2.44140625e-4f);
                u64 mqy = (u64)(unsigned int)rintf((float)sy * rcp * 2.44140625e-4f);
                u64 mqz = (u64)(unsigned int)rintf((float)sz * rcp * 3.0517578125e-5f);
                int lr = wrank[s >> 6] +
                         __popcll(msk[s >> 6] & ((1ULL << (s & 63)) - 1ULL));
                outv = mqx | (mqy << 14) | (mqz << 28) | ((u64)lr << 42);
            }
            pk[base + s] = outv;
        }
    }
    __syncthreads();                 // wrank dead; safe to reuse below
    // ---- last-block global prefix (replaces scan_bcnt dispatch) ----
    if (tid == 0) {
        __threadfence();
        int old = atomicAdd(done, 1);
        w0tot = (old == NBUCK - 1) ? 1 : 0;   // isLast flag
    }
    __syncthreads();
    if (w0tot) {
        __threadfence();             // acquire side
        int vv = 0;
        if (tid < NBUCK)
            vv = __hip_atomic_load(&bcnt[tid], __ATOMIC_RELAXED,
                                   __HIP_MEMORY_SCOPE_AGENT);
        int x = vv;
#pragma unroll
        for (int off = 1; off < 64; off <<= 1) {
            int y = __shfl_up(x, off, 64);
            if (lane >= off) x += y;
        }
        if (lane == 63) wrank[wv] = x;
        __syncthreads();
        if (wv == 0) {
            int w = (lane < 16) ? wrank[lane] : 0;
#pragma unroll
            for (int off = 1; off < 16; off <<= 1) {
                int y = __shfl_up(w, off, 64);
                if (lane >= off) w += y;
            }
            if (lane < 16) wrank[lane] = w;   // inclusive wave prefix
        }
        __syncthreads();
        int waveExcl = (wv == 0) ? 0 : wrank[wv - 1];
        if (tid < NBUCK) gbase[tid] = waveExcl + x - vv;
        if (tid == 0) {
            gbase[NBUCK] = wrank[15];   // total = num_unique
            gs[0] = 400.0f; gs[1] = 400.0f; gs[2] = 1.0f;
        }
    }
}

// Fused final kernel, 256 threads/block, three block-uniform roles.
// NO __launch_bounds__ (R9: forced VGPR cap -> spill).
__global__ void out_fused_kernel(const vf4* __restrict__ pts4, int n,
                                 const u64* __restrict__ pk,
                                 const int* __restrict__ gbase,
                                 const u64* __restrict__ gmask,
                                 float* __restrict__ feat,
                                 vf4* __restrict__ uinv4,
                                 vf4* __restrict__ unq4) {
    int bid = blockIdx.x;
    int tid = threadIdx.x;

    if (bid < NBUCK) {               // ---- unq-role ----
        __shared__ u64 mw[NWORDS];
        __shared__ int w0tot;
        int lane = tid & 63;
        if (tid < NWORDS) mw[tid] = gmask[(size_t)bid * NWORDS + tid];
        __syncthreads();
        int pc = 0, xi = 0;
        if (tid < NWORDS) {
            pc = __popcll(mw[tid]);
            xi = pc;
#pragma unroll
            for (int off = 1; off < 64; off <<= 1) {
                int y = __shfl_up(xi, off, 64);
                if (lane >= off) xi += y;
            }
            if (tid == 63) w0tot = xi;
        }
        __syncthreads();
        if (tid < NWORDS) {
            int r = gbase[bid] + xi - pc + ((tid >= 64) ? w0tot : 0);
            u64 w = mw[tid];
            int keyb = bid * TILE + tid * 64;
            while (w) {
                int bit = __builtin_ctzll(w);
                w &= w - 1;
                int k = keyb + bit;
                int tt = k % NT;
                int k2 = k / NT;
                int yy = k2 % GY;
                int k3 = k2 / GY;
                int xx = k3 % GX;
                int bb = k3 / GX;
                vf4 row = {(float)bb, (float)tt, (float)yy, (float)xx};
                unq4[r] = row;
                ++r;
            }
        }
        return;
    }

    if (bid < NBUCK + NPADBLK) {     // ---- pad-role ----
        int nu = gbase[NBUCK];
        vf4 neg = {-1.0f, -1.0f, -1.0f, -1.0f};
        for (int row = nu + (bid - NBUCK) * 256 + tid; row < n;
             row += NPADBLK * 256)
            unq4[row] = neg;
        return;
    }

    // ---- out-role: 8 points / thread ----
    int i = (bid - NBUCK - NPADBLK) * 256 + tid;
    int p0 = i * 8;
    if (p0 >= n) return;
    if (p0 + 7 < n) {
        // 12 independent nt loads first (max overlap), then keys, then all
        // 8 gathers + 8 L1-hot gbase loads issued back-to-back.
        vf4 A[12];
#pragma unroll
        for (int q = 0; q < 12; ++q)
            A[q] = __builtin_nontemporal_load(pts4 + (size_t)12 * i + q);
        float xs[8], ys[8], zs[8], is_[8];
        int key[8];
#pragma unroll
        for (int g = 0; g < 4; ++g) {
            vf4 v0 = A[3 * g], v1 = A[3 * g + 1], v2 = A[3 * g + 2];
            // point 2g:   b=v0.x x=v0.y y=v0.z z=v0.w i=v1.x t=v1.y
            // point 2g+1: b=v1.z x=v1.w y=v2.x z=v2.y i=v2.z t=v2.w
            xs[2 * g] = v0.y; ys[2 * g] = v0.z; zs[2 * g] = v0.w;
            is_[2 * g] = v1.x;
            key[2 * g] = (((int)v0.x * GX + (int)((v0.y + 50.0f) * 4.0f)) * GY
                          + (int)((v0.z + 50.0f) * 4.0f)) * NT + (int)v1.y;
            xs[2 * g + 1] = v1.w; ys[2 * g + 1] = v2.x; zs[2 * g + 1] = v2.y;
            is_[2 * g + 1] = v2.z;
            key[2 * g + 1] = (((int)v1.z * GX + (int)((v1.w + 50.0f) * 4.0f)) * GY
                              + (int)((v2.x + 50.0f) * 4.0f)) * NT + (int)v2.w;
        }
        u64 m[8];
        int rb[8];
#pragma unroll
        for (int k = 0; k < 8; ++k) m[k] = pk[key[k]];
#pragma unroll
        for (int k = 0; k < 8; ++k) rb[k] = gbase[key[k] / TILE];
        float r[8];
#pragma unroll
        for (int g = 0; g < 2; ++g) {
            float f[36];
#pragma unroll
            for (int k4 = 0; k4 < 4; ++k4) {
                int k = g * 4 + k4;
                u64 mm = m[k];
                const float qs = 1.0f / 16383.0f;
                float mdx = (float)(unsigned int)(mm & 0x3FFFULL) * qs;
                float mdy = (float)(unsigned int)((mm >> 14) & 0x3FFFULL) * qs;
                float mdz = (float)(unsigned int)((mm >> 28) & 0x3FFFULL) * qs;
                int cx = (int)((xs[k] + 50.0f) * 4.0f);
                int cy = (int)((ys[k] + 50.0f) * 4.0f);
                float bx = (float)cx * 0.25f - 50.0f;
                float by = (float)cy * 0.25f - 50.0f;
                float* fo = f + k4 * 9;
                fo[0] = xs[k];
                fo[1] = ys[k];
                fo[2] = zs[k];
                fo[3] = is_[k];
                fo[4] = xs[k] - (bx + mdx * 0.25f);
                fo[5] = ys[k] - (by + mdy * 0.25f);
                fo[6] = zs[k] - (-5.0f + mdz * 8.0f);
                fo[7] = xs[k] - (bx + 0.125f);
                fo[8] = ys[k] - (by + 0.125f);
                r[k] = (float)((unsigned int)(mm >> 42) + rb[k]);
            }
            vf4* dst = (vf4*)(feat + (size_t)i * 72 + g * 36);
#pragma unroll
            for (int q = 0; q < 9; ++q) {
                vf4 o = {f[4 * q], f[4 * q + 1], f[4 * q + 2], f[4 * q + 3]};
                dst[q] = o;
            }
        }
        vf4 rv0 = {r[0], r[1], r[2], r[3]};
        vf4 rv1 = {r[4], r[5], r[6], r[7]};
        uinv4[2 * i] = rv0;
        uinv4[2 * i + 1] = rv1;
    } else {
        const float* p = (const float*)pts4;
        float* uinv = (float*)uinv4;
        for (int j = p0; j < n && j < p0 + 8; ++j) {
            float x = p[6 * j + 1], y = p[6 * j + 2], z = p[6 * j + 3];
            float u = (x + 50.0f) * 4.0f;
            float v = (y + 50.0f) * 4.0f;
            int cx = (int)u, cy = (int)v;
            int key = (((int)p[6 * j] * GX + cx) * GY + cy) * NT + (int)p[6 * j + 5];
            u64 mm = pk[key];
            int rb = gbase[key / TILE];
            const float qs = 1.0f / 16383.0f;
            float mdx = (float)(unsigned int)(mm & 0x3FFFULL) * qs;
            float mdy = (float)(unsigned int)((mm >> 14) & 0x3FFFULL) * qs;
            float mdz = (float)(unsigned int)((mm >> 28) & 0x3FFFULL) * qs;
            float bx = (float)cx * 0.25f - 50.0f;
            float by = (float)cy * 0.25f - 50.0f;
            float fo[9];
            fo[0] = x; fo[1] = y; fo[2] = z; fo[3] = p[6 * j + 4];
            fo[4] = x - (bx + mdx * 0.25f);
            fo[5] = y - (by + mdy * 0.25f);
            fo[6] = z - (-5.0f + mdz * 8.0f);
            fo[7] = x - (bx + 0.125f);
            fo[8] = y - (by + 0.125f);
            for (int k = 0; k < 9; ++k) feat[(size_t)j * 9 + k] = fo[k];
            uinv[j] = (float)((unsigned int)(mm >> 42) + rb);
        }
    }
}

extern "C" void kernel_launch(void* const* d_in, const int* in_sizes, int n_in,
                              void* d_out, int out_size, void* d_ws, size_t ws_size,
                              hipStream_t stream) {
    const float* pts = (const float*)d_in[0];
    int n = in_sizes[0] / 6;       // 2,000,000

    char* ws = (char*)d_ws;
    u64* pk = (u64*)ws;                                  // NKEYS*8 = 25.6 MB
    int* gcnt  = (int*)(ws + (size_t)NKEYS * 8);         // 400 ints + done
    int* done  = gcnt + NBUCK;                           // 1 int (memset'd)
    int* bcnt  = (int*)(ws + (size_t)NKEYS * 8 + 2048);
    int* gbase = (int*)(ws + (size_t)NKEYS * 8 + 4096);  // 401 ints
    u64* gmask = (u64*)(ws + (size_t)NKEYS * 8 + 8192);  // 400*128*8 = 410KB

    float* feat = (float*)d_out;             // (n, 9)
    float* unq  = feat + (size_t)n * 9;      // (n, 4)
    float* uinv = feat + (size_t)n * 13;     // (n,)
    float* gs   = feat + (size_t)n * 14;     // (3,)

    // Records scratch (400*5632*8B = 18MB) aliases the feat region; feat is
    // only written by out_fused after bucket_accum consumed the records.
    u64* recs = (u64*)d_out;

    (void)hipMemsetAsync(gcnt, 0, 2048, stream);         // gcnt + done

    int nb_bin = (n + BINPTS - 1) / BINPTS;              // 489
    bin_kernel<<<nb_bin, 1024, 0, stream>>>((const vf4*)pts, n, gcnt, recs);
    bucket_accum_kernel<<<NBUCK, 1024, 0, stream>>>(recs, gcnt, pk, bcnt, gmask,
                                                    done, gbase, gs);

    int nt8 = (n + 7) / 8;
    int nb_out = (nt8 + 255) / 256;                      // 977
    out_fused_kernel<<<NBUCK + NPADBLK + nb_out, 256, 0, stream>>>(
        (const vf4*)pts, n, pk, gbase, gmask, feat, (vf4*)uinv, (vf4*)unq);
}

// Round 8
// 295.761 us; speedup vs baseline: 1.0757x; 1.0757x over previous
//
#include <hip/hip_runtime.h>

// PillarMotionNet voxelization for MI355X.
// Dense key space: 4 * 400 * 400 * 5 = 3.2M keys; 2M points.
//
// Measured walls:
//  - ATOMICS (device-scope RMW) run ~21 G/s, payload/locality-invariant —
//    bypass L2 write-combining. PLAIN stores, even scattered 8B, DO combine
//    in L2 (R12: coalescing bin's record writes was a no-op; R6: nt stores
//    defeat combining -> plain stores only, nt loads fine).
//  - R7: out gather: 2M random 8B gathers from 25.6MB pk ~= 100MB HBM fetch
//    (line-granularity floor, matches 1-e^-λ model), concurrency-bound at
//    ~3.2TB/s.
//  - R8: cooperative fusion REGRESSION: grid-wide sync at <2 blk/CU.
//  - R9+R13: >4 pts/thread in the out body ALWAYS spills (~128B/thread
//    scratch, FETCH +30..100MB), with or without launch_bounds. 4pt/thread,
//    VGPR 32, 93.5us — proven twice. DO NOT exceed 4.
//  - R10: static LDS must stay <= 65,536B per workgroup.
//  - R13: merging the tiny scan dispatch into accum's last block: neutral.
//
// Pipeline (3 dispatches, NO memset):
//  bin_kernel     489 blks x 1024thr x 4pt: nt-load 48MB; LDS hist; block
//                 scan; LDS counting sort; DETERMINISTIC segment write:
//                 bucket b of block bid -> recs[(b*SEGS+bid)*40 .. +40),
//                 counts -> gbcnt[bid*400+b] (coalesced). No global atomics.
//                 Block 0 zeroes the done counter (consumed next kernel).
//  bucket_accum   reads its bucket's 19,560-slot strip predicated by gbcnt
//                 (segments 320B line-aligned -> ~25MB fetch); LDS-atomic
//                 accumulate; ballot mask; popcount scan -> LOCAL ranks;
//                 write pk dense FINAL-PACKED + gmask + bcnt; LAST block
//                 (done counter) computes gbase[401] + nu + grid-size.
//  out_fused      unq-role (400 blks) + pad-role (128 blks) + out-role
//                 (4pt/thread proven body; rank = local + gbase[key/8000]).
//
// Record: [0:21] key  [22:34] qdx (*4096)  [35:47] qdy  [48:63] qdz (*32768)
// Accumulator (LDS): [0:17] sum qdx [18:35] sum qdy [36:56] sum qdz [57:63] cnt
// pk packed: [0:13] mqx  [14:27] mqy  [28:41] mqz  [42:54] local rank
// recs (62.6MB) + gbcnt (0.78MB @ +80MB) alias d_out's feat/unq regions;
// both fully consumed by bucket_accum before out_fused writes them.

#define NKEYS 3200000
#define GX 400
#define GY 400
#define NT 5

#define NBUCK 400
#define TILE 8000        // keys per bucket; NBUCK * TILE == NKEYS
#define SEGCAP 40        // records per (block,bucket) segment; lambda=10.24,
                         // P(overflow)~5e-12/cell -> ~1e-6/run
#define NWORDS 128       // gmask stride (64-bit words per bucket)
#define MWORDS 125       // words covering slots [0,8000)
#define NPADBLK 128
#define BINPTS 4096      // points per bin block (1024 thr x 4)

typedef __attribute__((ext_vector_type(4))) float vf4;
typedef unsigned long long u64;

__device__ __forceinline__ void make_rec(float b, float x, float y, float z,
                                         float t, int* bkt, u64* rec) {
    float u = (x + 50.0f) * 4.0f;
    float v = (y + 50.0f) * 4.0f;
    int cx = (int)u;
    int cy = (int)v;
    float dx = u - (float)cx;              // exact, in [0,1)
    float dy = v - (float)cy;
    float dz = (z + 5.0f) * 0.125f;        // [0,1)
    int key = (((int)b * GX + cx) * GY + cy) * NT + (int)t;
    u64 qdx = (u64)(unsigned int)rintf(dx * 4096.0f);    // <= 4096, 13 bits
    u64 qdy = (u64)(unsigned int)rintf(dy * 4096.0f);
    u64 qdz = (u64)(unsigned int)rintf(dz * 32768.0f);   // <= 32768, 16 bits
    *bkt = key / TILE;
    *rec = (u64)(unsigned int)key | (qdx << 22) | (qdy << 35) | (qdz << 48);
}

// Block-local counting sort -> deterministic per-(block,bucket) segments.
// LDS: 32768 (lrec) + 3*1600 + 64 + 4 = 37,636 B.
__global__ __launch_bounds__(1024) void bin_kernel(const vf4* __restrict__ pts4,
                                                   int n, int nsegs,
                                                   int* __restrict__ gbcnt,
                                                   u64* __restrict__ recs,
                                                   int* __restrict__ done) {
    __shared__ u64 lrec[BINPTS];
    __shared__ int hist[NBUCK];
    __shared__ int pref[NBUCK];
    __shared__ int dlt[NBUCK];
    __shared__ int wsum[16];
    __shared__ int sTotal;
    int tid = threadIdx.x;
    int lane = tid & 63;
    int wv = tid >> 6;              // 0..15
    int bid = blockIdx.x;
    if (bid == 0 && tid == 0)       // init for bucket_accum's last-block logic
        __hip_atomic_store(done, 0, __ATOMIC_RELAXED, __HIP_MEMORY_SCOPE_AGENT);
    if (tid < NBUCK) hist[tid] = 0;
    __syncthreads();

    int i = bid * 1024 + tid;
    int p0 = i * 4;
    int bkt[4];
    u64 rec[4];
    int lrk[4];
    int nv = 0;
    if (p0 + 3 < n) {
        vf4 a0 = __builtin_nontemporal_load(pts4 + (size_t)6 * i + 0);
        vf4 a1 = __builtin_nontemporal_load(pts4 + (size_t)6 * i + 1);
        vf4 a2 = __builtin_nontemporal_load(pts4 + (size_t)6 * i + 2);
        vf4 a3 = __builtin_nontemporal_load(pts4 + (size_t)6 * i + 3);
        vf4 a4 = __builtin_nontemporal_load(pts4 + (size_t)6 * i + 4);
        vf4 a5 = __builtin_nontemporal_load(pts4 + (size_t)6 * i + 5);
        make_rec(a0.x, a0.y, a0.z, a0.w, a1.y, &bkt[0], &rec[0]);
        make_rec(a1.z, a1.w, a2.x, a2.y, a2.w, &bkt[1], &rec[1]);
        make_rec(a3.x, a3.y, a3.z, a3.w, a4.y, &bkt[2], &rec[2]);
        make_rec(a4.z, a4.w, a5.x, a5.y, a5.w, &bkt[3], &rec[3]);
        nv = 4;
    } else if (p0 < n) {
        const float* p = (const float*)pts4;
#pragma unroll
        for (int k = 0; k < 4; ++k) {
            int j = p0 + k;
            if (j < n) {
                make_rec(p[6 * j], p[6 * j + 1], p[6 * j + 2], p[6 * j + 3],
                         p[6 * j + 5], &bkt[k], &rec[k]);
                nv = k + 1;
            }
        }
    }
#pragma unroll
    for (int k = 0; k < 4; ++k)
        if (k < nv) lrk[k] = atomicAdd(&hist[bkt[k]], 1);
    __syncthreads();

    // block scan of the 400 bucket counts (tid >= 400 contribute 0)
    int v = (tid < NBUCK) ? hist[tid] : 0;
    int x = v;
#pragma unroll
    for (int off = 1; off < 64; off <<= 1) {
        int y = __shfl_up(x, off, 64);
        if (lane >= off) x += y;
    }
    if (lane == 63) wsum[wv] = x;
    __syncthreads();
    if (wv == 0) {
        int w = (lane < 16) ? wsum[lane] : 0;
#pragma unroll
        for (int off = 1; off < 16; off <<= 1) {
            int y = __shfl_up(w, off, 64);
            if (lane >= off) w += y;
        }
        if (lane < 16) wsum[lane] = w;   // inclusive wave prefix
    }
    __syncthreads();
    int waveExcl = (wv == 0) ? 0 : wsum[wv - 1];
    int excl = waveExcl + x - v;
    if (tid < NBUCK) {
        pref[tid] = excl;
        // deterministic segment base for (bucket=tid, block=bid)
        dlt[tid] = (tid * nsegs + bid) * SEGCAP - excl;
        gbcnt[bid * NBUCK + tid] = v;    // coalesced 1.6KB per block
    }
    if (tid == 1023) sTotal = waveExcl + x;  // total records in block
    __syncthreads();

    // scatter into LDS, sorted by bucket (slot order == bucket-run order)
#pragma unroll
    for (int k = 0; k < 4; ++k)
        if (k < nv) lrec[pref[bkt[k]] + lrk[k]] = rec[k];
    __syncthreads();

    // linear write-out: consecutive threads -> consecutive slots -> segments
    int tot = sTotal;
#pragma unroll
    for (int j = 0; j < 4; ++j) {
        int slot = tid + j * 1024;
        if (slot < tot) {
            u64 rc = lrec[slot];
            int key = (int)(rc & 0x3FFFFFULL);
            int bk = key / TILE;             // magic-mul division
            if (slot - pref[bk] < SEGCAP)    // statistically impossible guard
                recs[(size_t)(dlt[bk] + slot)] = rc;
        }
    }
}

// One block per bucket. Reads its 19,560-slot strip predicated by gbcnt;
// LDS accumulate; ballot present-mask; popcount scan -> local ranks; write
// pk dense final-packed + gmask + bcnt. LAST block computes gbase[401]+nu+gs.
// Static LDS: 64000 + 1000 + 500 + 4 = 65,504 B (limit 65,536).
__global__ __launch_bounds__(1024) void bucket_accum_kernel(
        const u64* __restrict__ recs, const int* __restrict__ gbcnt, int nsegs,
        u64* __restrict__ pk, int* __restrict__ bcnt, u64* __restrict__ gmask,
        int* __restrict__ done, int* __restrict__ gbase,
        float* __restrict__ gs) {
    __shared__ u64 tbl[TILE];       // 64,000 B
    __shared__ u64 msk[MWORDS];     // present bitmask, words 0..124
    __shared__ int wrank[MWORDS];   // excl rank at word start; reused by scan
    __shared__ int w0tot;           // reused as isLast flag
    int tid = threadIdx.x;
    int lane = tid & 63;
    int wv = tid >> 6;              // 0..15
    int b = blockIdx.x;
    for (int s = tid; s < TILE; s += 1024) tbl[s] = 0;
    __syncthreads();
    int strip = nsegs * SEGCAP;                       // 19,560
    const u64* rp = recs + (size_t)b * strip;
    int base = b * TILE;
    for (int idx = tid; idx < strip; idx += 1024) {
        int seg = idx / SEGCAP;
        int off = idx - seg * SEGCAP;
        int cs = gbcnt[seg * NBUCK + b];              // L2-hot (0.78MB table)
        if (off < cs) {
            u64 v = __builtin_nontemporal_load(rp + idx);
            int slot = (int)(v & 0x3FFFFFULL) - base;
            u64 qdx = (v >> 22) & 0x1FFFULL;
            u64 qdy = (v >> 35) & 0x1FFFULL;
            u64 qdz = v >> 48;
            atomicAdd(&tbl[slot], qdx | (qdy << 18) | (qdz << 36) | (1ULL << 57));
        }
    }
    __syncthreads();
    // present-mask via ballot; lanes of a wave cover 64 consecutive slots.
#pragma unroll
    for (int j = 0; j < 8; ++j) {
        int s = tid + j * 1024;
        bool p = (s < TILE) && (tbl[s] != 0ULL);
        u64 bal = __ballot(p);
        int w = s >> 6;                     // = j*16 + wave
        if (lane == 0 && w < MWORDS) msk[w] = bal;
    }
    __syncthreads();
    // exclusive prefix over 125 word popcounts (threads 0..124)
    int pc = 0, xi = 0;
    if (tid < MWORDS) {
        pc = __popcll(msk[tid]);
        xi = pc;
#pragma unroll
        for (int off = 1; off < 64; off <<= 1) {
            int y = __shfl_up(xi, off, 64);
            if (lane >= off) xi += y;
        }
        if (tid == 63) w0tot = xi;
    }
    __syncthreads();
    if (tid < MWORDS) {
        int add = (tid >= 64) ? w0tot : 0;
        wrank[tid] = xi - pc + add;
        if (tid == MWORDS - 1)              // bucket unique count, release
            __hip_atomic_store(&bcnt[b], xi + add, __ATOMIC_RELEASE,
                               __HIP_MEMORY_SCOPE_AGENT);
        gmask[(size_t)b * NWORDS + tid] = msk[tid];
    } else if (tid < NWORDS) {
        gmask[(size_t)b * NWORDS + tid] = 0ULL;      // structural zeros
    }
    __syncthreads();
    // final-packed pk write; strided tile reads (conflict-free); full lines.
#pragma unroll
    for (int j = 0; j < 8; ++j) {
        int s = tid + j * 1024;
        if (s < TILE) {
            u64 v = tbl[s];
            u64 outv = 0ULL;
            if (v) {
                float cntf = (float)(unsigned int)(v >> 57);
                float rcp = 16383.0f / cntf;
                unsigned int sx = (unsigned int)(v & 0x3FFFFULL);
                unsigned int sy = (unsigned int)((v >> 18) & 0x3FFFFULL);
                unsigned int sz = (unsigned int)((v >> 36) & 0x1FFFFFULL);
                u64 mqx = (u64)(unsigned int)rintf((float)sx * rcp * 2.44140625e-4f);
                u64 mqy = (u64)(unsigned int)rintf((float)sy * rcp * 2.44140625e-4f);
                u64 mqz = (u64)(unsigned int)rintf((float)sz * rcp * 3.0517578125e-5f);
                int lr = wrank[s >> 6] +
                         __popcll(msk[s >> 6] & ((1ULL << (s & 63)) - 1ULL));
                outv = mqx | (mqy << 14) | (mqz << 28) | ((u64)lr << 42);
            }
            pk[base + s] = outv;
        }
    }
    __syncthreads();                 // wrank dead; safe to reuse below
    // ---- last-block global prefix (no extra dispatch) ----
    if (tid == 0) {
        __threadfence();
        int old = atomicAdd(done, 1);
        w0tot = (old == NBUCK - 1) ? 1 : 0;   // isLast flag
    }
    __syncthreads();
    if (w0tot) {
        __threadfence();             // acquire side
        int vv = 0;
        if (tid < NBUCK)
            vv = __hip_atomic_load(&bcnt[tid], __ATOMIC_RELAXED,
                                   __HIP_MEMORY_SCOPE_AGENT);
        int x = vv;
#pragma unroll
        for (int off = 1; off < 64; off <<= 1) {
            int y = __shfl_up(x, off, 64);
            if (lane >= off) x += y;
        }
        if (lane == 63) wrank[wv] = x;
        __syncthreads();
        if (wv == 0) {
            int w = (lane < 16) ? wrank[lane] : 0;
#pragma unroll
            for (int off = 1; off < 16; off <<= 1) {
                int y = __shfl_up(w, off, 64);
                if (lane >= off) w += y;
            }
            if (lane < 16) wrank[lane] = w;   // inclusive wave prefix
        }
        __syncthreads();
        int waveExcl = (wv == 0) ? 0 : wrank[wv - 1];
        if (tid < NBUCK) gbase[tid] = waveExcl + x - vv;
        if (tid == 0) {
            gbase[NBUCK] = wrank[15];   // total = num_unique
            gs[0] = 400.0f; gs[1] = 400.0f; gs[2] = 1.0f;
        }
    }
}

__device__ __forceinline__ void point_feat(float bfl, float x, float y, float z,
                                           float inten, float t,
                                           const u64* __restrict__ pk,
                                           const int* __restrict__ gbase,
                                           float* f, float* r) {
    float u = (x + 50.0f) * 4.0f;
    float v = (y + 50.0f) * 4.0f;
    int cx = (int)u;
    int cy = (int)v;
    int key = (((int)bfl * GX + cx) * GY + cy) * NT + (int)t;
    u64 m = pk[key];                   // [mqx|mqy|mqz|local rank]
    int bb = gbase[key / TILE];        // 1.6KB table, L1-resident
    const float qs = 1.0f / 16383.0f;
    float mdx = (float)(unsigned int)(m & 0x3FFFULL) * qs;
    float mdy = (float)(unsigned int)((m >> 14) & 0x3FFFULL) * qs;
    float mdz = (float)(unsigned int)((m >> 28) & 0x3FFFULL) * qs;
    float bx = (float)cx * 0.25f - 50.0f;
    float by = (float)cy * 0.25f - 50.0f;
    f[0] = x;
    f[1] = y;
    f[2] = z;
    f[3] = inten;
    f[4] = x - (bx + mdx * 0.25f);
    f[5] = y - (by + mdy * 0.25f);
    f[6] = z - (-5.0f + mdz * 8.0f);
    f[7] = x - (bx + 0.125f);
    f[8] = y - (by + 0.125f);
    *r = (float)((unsigned int)(m >> 42) + bb);
}

// Fused final kernel, 256 threads/block, three block-uniform roles.
// out-role is the twice-proven 4pt/thread body (R9/R13: >4pt always spills).
__global__ void out_fused_kernel(const vf4* __restrict__ pts4, int n,
                                 const u64* __restrict__ pk,
                                 const int* __restrict__ gbase,
                                 const u64* __restrict__ gmask,
                                 float* __restrict__ feat,
                                 vf4* __restrict__ uinv4,
                                 vf4* __restrict__ unq4) {
    int bid = blockIdx.x;
    int tid = threadIdx.x;

    if (bid < NBUCK) {               // ---- unq-role ----
        __shared__ u64 mw[NWORDS];
        __shared__ int w0tot;
        int lane = tid & 63;
        if (tid < NWORDS) mw[tid] = gmask[(size_t)bid * NWORDS + tid];
        __syncthreads();
        int pc = 0, xi = 0;
        if (tid < NWORDS) {
            pc = __popcll(mw[tid]);
            xi = pc;
#pragma unroll
            for (int off = 1; off < 64; off <<= 1) {
                int y = __shfl_up(xi, off, 64);
                if (lane >= off) xi += y;
            }
            if (tid == 63) w0tot = xi;
        }
        __syncthreads();
        if (tid < NWORDS) {
            int r = gbase[bid] + xi - pc + ((tid >= 64) ? w0tot : 0);
            u64 w = mw[tid];
            int keyb = bid * TILE + tid * 64;
            while (w) {
                int bit = __builtin_ctzll(w);
                w &= w - 1;
                int k = keyb + bit;
                int tt = k % NT;
                int k2 = k / NT;
                int yy = k2 % GY;
                int k3 = k2 / GY;
                int xx = k3 % GX;
                int bb = k3 / GX;
                vf4 row = {(float)bb, (float)tt, (float)yy, (float)xx};
                unq4[r] = row;
                ++r;
            }
        }
        return;
    }

    if (bid < NBUCK + NPADBLK) {     // ---- pad-role ----
        int nu = gbase[NBUCK];
        vf4 neg = {-1.0f, -1.0f, -1.0f, -1.0f};
        for (int row = nu + (bid - NBUCK) * 256 + tid; row < n;
             row += NPADBLK * 256)
            unq4[row] = neg;
        return;
    }

    // ---- out-role: 4 points / thread (proven body) ----
    int i = (bid - NBUCK - NPADBLK) * 256 + tid;
    int p0 = i * 4;
    if (p0 >= n) return;
    if (p0 + 3 < n) {
        vf4 a0 = __builtin_nontemporal_load(pts4 + (size_t)6 * i + 0);
        vf4 a1 = __builtin_nontemporal_load(pts4 + (size_t)6 * i + 1);
        vf4 a2 = __builtin_nontemporal_load(pts4 + (size_t)6 * i + 2);
        vf4 a3 = __builtin_nontemporal_load(pts4 + (size_t)6 * i + 3);
        vf4 a4 = __builtin_nontemporal_load(pts4 + (size_t)6 * i + 4);
        vf4 a5 = __builtin_nontemporal_load(pts4 + (size_t)6 * i + 5);
        float f[36];
        float r[4];
        point_feat(a0.x, a0.y, a0.z, a0.w, a1.x, a1.y, pk, gbase, f + 0, r + 0);
        point_feat(a1.z, a1.w, a2.x, a2.y, a2.z, a2.w, pk, gbase, f + 9, r + 1);
        point_feat(a3.x, a3.y, a3.z, a3.w, a4.x, a4.y, pk, gbase, f + 18, r + 2);
        point_feat(a4.z, a4.w, a5.x, a5.y, a5.z, a5.w, pk, gbase, f + 27, r + 3);
        vf4* dst = (vf4*)(feat + (size_t)i * 36);  // 144B/thread, 16B aligned
#pragma unroll
        for (int k = 0; k < 9; ++k) {
            vf4 o = {f[4 * k], f[4 * k + 1], f[4 * k + 2], f[4 * k + 3]};
            dst[k] = o;
        }
        vf4 rv = {r[0], r[1], r[2], r[3]};
        uinv4[i] = rv;
    } else {
        const float* p = (const float*)pts4;
        float* uinv = (float*)uinv4;
        for (int j = p0; j < n; ++j) {
            float f[9];
            float r;
            point_feat(p[6 * j], p[6 * j + 1], p[6 * j + 2], p[6 * j + 3],
                       p[6 * j + 4], p[6 * j + 5], pk, gbase, f, &r);
            for (int k = 0; k < 9; ++k) feat[(size_t)j * 9 + k] = f[k];
            uinv[j] = r;
        }
    }
}

extern "C" void kernel_launch(void* const* d_in, const int* in_sizes, int n_in,
                              void* d_out, int out_size, void* d_ws, size_t ws_size,
                              hipStream_t stream) {
    const float* pts = (const float*)d_in[0];
    int n = in_sizes[0] / 6;       // 2,000,000

    char* ws = (char*)d_ws;
    u64* pk = (u64*)ws;                                  // NKEYS*8 = 25.6 MB
    int* done  = (int*)(ws + (size_t)NKEYS * 8);         // zeroed by bin blk 0
    int* bcnt  = (int*)(ws + (size_t)NKEYS * 8 + 2048);
    int* gbase = (int*)(ws + (size_t)NKEYS * 8 + 4096);  // 401 ints
    u64* gmask = (u64*)(ws + (size_t)NKEYS * 8 + 8192);  // 400*128*8 = 410KB

    float* feat = (float*)d_out;             // (n, 9)
    float* unq  = feat + (size_t)n * 9;      // (n, 4)
    float* uinv = feat + (size_t)n * 13;     // (n,)
    float* gs   = feat + (size_t)n * 14;     // (3,)

    int nsegs = (n + BINPTS - 1) / BINPTS;               // 489 bin blocks
    // recs: NBUCK * nsegs * SEGCAP * 8B = 62.6MB, aliases feat region;
    // gbcnt: nsegs*400 ints at +80MB (inside unq region). Both consumed by
    // bucket_accum before out_fused writes feat/unq. Stream-ordered, safe.
    u64* recs = (u64*)d_out;
    int* gbcnt = (int*)((char*)d_out + (size_t)80 * 1024 * 1024);

    bin_kernel<<<nsegs, 1024, 0, stream>>>((const vf4*)pts, n, nsegs,
                                           gbcnt, recs, done);
    bucket_accum_kernel<<<NBUCK, 1024, 0, stream>>>(recs, gbcnt, nsegs, pk,
                                                    bcnt, gmask, done, gbase, gs);

    int nq = (n + 3) / 4;
    int nb_out = (nq + 255) / 256;                       // 1954
    out_fused_kernel<<<NBUCK + NPADBLK + nb_out, 256, 0, stream>>>(
        (const vf4*)pts, n, pk, gbase, gmask, feat, (vf4*)uinv, (vf4*)unq);
}

// Round 9
// 257.799 us; speedup vs baseline: 1.2341x; 1.1473x over previous
//
#include <hip/hip_runtime.h>

// PillarMotionNet voxelization for MI355X.
// Dense key space: 4 * 400 * 400 * 5 = 3.2M keys; 2M points.
//
// Measured walls:
//  - ATOMICS (device-scope RMW) run ~21 G/s, payload/locality-invariant —
//    bypass L2 write-combining. PLAIN stores, even scattered 8B, DO combine
//    in L2 (R12). nt stores defeat combining -> plain stores only; nt loads ok.
//  - Random 8B gathers from 25.6MB pk: ~100MB HBM line fetch; R1's out ran
//    them at 26.7G lines/s (75us) -> NOT hard-walled at 21G/s.
//  - R8: cooperative fusion REGRESSION (grid sync at <2 blk/CU).
//  - R9+R13: >4 pts/thread in the out body ALWAYS spills. 4pt, VGPR 32. Keep.
//  - R10: static LDS <= 65,536B per workgroup.
//  - R14: deterministic sparse segments REGRESSION (296): partial-line island
//    writes + predicated strip reads. Dense RCAP strips + gcnt atomics win.
//  - R14: front-running role-blocks in the final kernel cost ~20us (serial
//    unq/pad roles occupy all CUs before gathers start). Fix: out-role first,
//    pad folded into out threads (R1-proven), unq-role as tail blocks.
//
// Pipeline (5 dispatches) — R6-proven middle, reordered final kernel:
//  memset(gcnt 1.6KB)
//  bin_kernel     489x1024x4pt: nt-load 48MB; LDS hist; block scan; 1 global
//                 atomic per (block,bucket); LDS counting sort; linear write
//                 of dense per-bucket runs into RCAP strips.
//  bucket_accum   16MB read; LDS-atomic accumulate; ballot present-mask;
//                 popcount scan -> LOCAL ranks; pk dense FINAL-PACKED +
//                 gmask(410KB) + bcnt.
//  scan_bcnt      1 block: gbase[401] = excl prefix of bcnt; nu; grid-size.
//  out_fused      bid<nb_out: out-role = R1 4pt body (gather pk, +gbase
//                 L1-table for global rank, feat+uinv+self-pad of unq).
//                 tail 400 blocks: unq-role (decode gmask -> unq rows).
//
// Record: [0:21] key  [22:34] qdx (*4096)  [35:47] qdy  [48:63] qdz (*32768)
// Accumulator (LDS): [0:17] sum qdx [18:35] sum qdy [36:56] sum qdz [57:63] cnt
// pk packed: [0:13] mqx  [14:27] mqy  [28:41] mqz  [42:54] local rank
// Absent pk slots hold 0; never read (every gathered key is present).
// recs (18MB) aliases d_out's feat region (accum consumes before out writes).

#define NKEYS 3200000
#define GX 400
#define GY 400
#define NT 5

#define NBUCK 400
#define TILE 8000        // keys per bucket; NBUCK * TILE == NKEYS
#define RCAP 5632        // records per bucket: mean 5000, sd ~71 (+8.9 sigma)
#define NWORDS 128       // gmask stride (64-bit words per bucket)
#define MWORDS 125       // words covering slots [0,8000)
#define BINPTS 4096      // points per bin block (1024 thr x 4)

typedef __attribute__((ext_vector_type(4))) float vf4;
typedef unsigned long long u64;

__device__ __forceinline__ void make_rec(float b, float x, float y, float z,
                                         float t, int* bkt, u64* rec) {
    float u = (x + 50.0f) * 4.0f;
    float v = (y + 50.0f) * 4.0f;
    int cx = (int)u;
    int cy = (int)v;
    float dx = u - (float)cx;              // exact, in [0,1)
    float dy = v - (float)cy;
    float dz = (z + 5.0f) * 0.125f;        // [0,1)
    int key = (((int)b * GX + cx) * GY + cy) * NT + (int)t;
    u64 qdx = (u64)(unsigned int)rintf(dx * 4096.0f);    // <= 4096, 13 bits
    u64 qdy = (u64)(unsigned int)rintf(dy * 4096.0f);
    u64 qdz = (u64)(unsigned int)rintf(dz * 32768.0f);   // <= 32768, 16 bits
    *bkt = key / TILE;
    *rec = (u64)(unsigned int)key | (qdx << 22) | (qdy << 35) | (qdz << 48);
}

// Block-local counting sort -> coalesced dense per-bucket run writes.
// LDS: 32768 (lrec) + 3*1600 + 64 + 4 = 37,636 B.
__global__ __launch_bounds__(1024) void bin_kernel(const vf4* __restrict__ pts4,
                                                   int n, int* __restrict__ gcnt,
                                                   u64* __restrict__ recs) {
    __shared__ u64 lrec[BINPTS];
    __shared__ int hist[NBUCK];
    __shared__ int pref[NBUCK];
    __shared__ int dlt[NBUCK];
    __shared__ int wsum[16];
    __shared__ int sTotal;
    int tid = threadIdx.x;
    int lane = tid & 63;
    int wv = tid >> 6;              // 0..15
    if (tid < NBUCK) hist[tid] = 0;
    __syncthreads();

    int i = blockIdx.x * 1024 + tid;
    int p0 = i * 4;
    int bkt[4];
    u64 rec[4];
    int lrk[4];
    int nv = 0;
    if (p0 + 3 < n) {
        vf4 a0 = __builtin_nontemporal_load(pts4 + (size_t)6 * i + 0);
        vf4 a1 = __builtin_nontemporal_load(pts4 + (size_t)6 * i + 1);
        vf4 a2 = __builtin_nontemporal_load(pts4 + (size_t)6 * i + 2);
        vf4 a3 = __builtin_nontemporal_load(pts4 + (size_t)6 * i + 3);
        vf4 a4 = __builtin_nontemporal_load(pts4 + (size_t)6 * i + 4);
        vf4 a5 = __builtin_nontemporal_load(pts4 + (size_t)6 * i + 5);
        make_rec(a0.x, a0.y, a0.z, a0.w, a1.y, &bkt[0], &rec[0]);
        make_rec(a1.z, a1.w, a2.x, a2.y, a2.w, &bkt[1], &rec[1]);
        make_rec(a3.x, a3.y, a3.z, a3.w, a4.y, &bkt[2], &rec[2]);
        make_rec(a4.z, a4.w, a5.x, a5.y, a5.w, &bkt[3], &rec[3]);
        nv = 4;
    } else if (p0 < n) {
        const float* p = (const float*)pts4;
#pragma unroll
        for (int k = 0; k < 4; ++k) {
            int j = p0 + k;
            if (j < n) {
                make_rec(p[6 * j], p[6 * j + 1], p[6 * j + 2], p[6 * j + 3],
                         p[6 * j + 5], &bkt[k], &rec[k]);
                nv = k + 1;
            }
        }
    }
#pragma unroll
    for (int k = 0; k < 4; ++k)
        if (k < nv) lrk[k] = atomicAdd(&hist[bkt[k]], 1);
    __syncthreads();

    // block scan of the 400 bucket counts (tid >= 400 contribute 0)
    int v = (tid < NBUCK) ? hist[tid] : 0;
    int x = v;
#pragma unroll
    for (int off = 1; off < 64; off <<= 1) {
        int y = __shfl_up(x, off, 64);
        if (lane >= off) x += y;
    }
    if (lane == 63) wsum[wv] = x;
    __syncthreads();
    if (wv == 0) {
        int w = (lane < 16) ? wsum[lane] : 0;
#pragma unroll
        for (int off = 1; off < 16; off <<= 1) {
            int y = __shfl_up(w, off, 64);
            if (lane >= off) w += y;
        }
        if (lane < 16) wsum[lane] = w;   // inclusive wave prefix
    }
    __syncthreads();
    int waveExcl = (wv == 0) ? 0 : wsum[wv - 1];
    int excl = waveExcl + x - v;
    if (tid < NBUCK) {
        pref[tid] = excl;
        int gb = atomicAdd(&gcnt[tid], v);   // reserve this block's run
        dlt[tid] = gb - excl;                // slot -> in-bucket position
    }
    if (tid == 1023) sTotal = waveExcl + x;  // total records in block
    __syncthreads();

    // scatter into LDS, sorted by bucket (slot order == bucket-run order)
#pragma unroll
    for (int k = 0; k < 4; ++k)
        if (k < nv) lrec[pref[bkt[k]] + lrk[k]] = rec[k];
    __syncthreads();

    // linear write-out: consecutive threads -> consecutive slots -> runs
    int tot = sTotal;
#pragma unroll
    for (int j = 0; j < 4; ++j) {
        int slot = tid + j * 1024;
        if (slot < tot) {
            u64 rc = lrec[slot];
            int key = (int)(rc & 0x3FFFFFULL);
            int bk = key / TILE;             // magic-mul division
            int gpos = dlt[bk] + slot;
            if (gpos < RCAP)                 // statistically impossible guard
                recs[(size_t)bk * RCAP + gpos] = rc;
        }
    }
}

// One block per bucket. LDS accumulate; ballot present-mask on strided
// (conflict-free) tile reads; exclusive word-popcount scan -> local ranks;
// write pk dense final-packed (full lines, zeros for absent), gmask, bcnt.
// Static LDS: 64000 + 1000 + 500 + 4 = 65,504 B (limit 65,536).
__global__ __launch_bounds__(1024) void bucket_accum_kernel(
        const u64* __restrict__ recs, const int* __restrict__ gcnt,
        u64* __restrict__ pk, int* __restrict__ bcnt, u64* __restrict__ gmask) {
    __shared__ u64 tbl[TILE];       // 64,000 B
    __shared__ u64 msk[MWORDS];     // present bitmask, words 0..124
    __shared__ int wrank[MWORDS];   // exclusive rank at word start
    __shared__ int w0tot;
    int tid = threadIdx.x;
    int lane = tid & 63;
    int b = blockIdx.x;
    for (int s = tid; s < TILE; s += 1024) tbl[s] = 0;
    __syncthreads();
    int cnt = gcnt[b];
    if (cnt > RCAP) cnt = RCAP;
    const u64* rp = recs + (size_t)b * RCAP;
    int base = b * TILE;
    for (int r = tid; r < cnt; r += 1024) {
        u64 v = __builtin_nontemporal_load(rp + r);
        int slot = (int)(v & 0x3FFFFFULL) - base;
        u64 qdx = (v >> 22) & 0x1FFFULL;
        u64 qdy = (v >> 35) & 0x1FFFULL;
        u64 qdz = v >> 48;
        atomicAdd(&tbl[slot], qdx | (qdy << 18) | (qdz << 36) | (1ULL << 57));
    }
    __syncthreads();
    // present-mask via ballot; lanes of a wave cover 64 consecutive slots.
#pragma unroll
    for (int j = 0; j < 8; ++j) {
        int s = tid + j * 1024;
        bool p = (s < TILE) && (tbl[s] != 0ULL);
        u64 bal = __ballot(p);
        int w = s >> 6;                     // = j*16 + wave
        if (lane == 0 && w < MWORDS) msk[w] = bal;
    }
    __syncthreads();
    // exclusive prefix over 125 word popcounts (threads 0..124)
    int pc = 0, xi = 0;
    if (tid < MWORDS) {
        pc = __popcll(msk[tid]);
        xi = pc;
#pragma unroll
        for (int off = 1; off < 64; off <<= 1) {
            int y = __shfl_up(xi, off, 64);
            if (lane >= off) xi += y;
        }
        if (tid == 63) w0tot = xi;
    }
    __syncthreads();
    if (tid < MWORDS) {
        int add = (tid >= 64) ? w0tot : 0;
        wrank[tid] = xi - pc + add;
        if (tid == MWORDS - 1) bcnt[b] = xi + add;   // bucket unique count
        gmask[(size_t)b * NWORDS + tid] = msk[tid];
    } else if (tid < NWORDS) {
        gmask[(size_t)b * NWORDS + tid] = 0ULL;      // structural zeros
    }
    __syncthreads();
    // final-packed pk write; strided tile reads (conflict-free); full lines.
#pragma unroll
    for (int j = 0; j < 8; ++j) {
        int s = tid + j * 1024;
        if (s < TILE) {
            u64 v = tbl[s];
            u64 outv = 0ULL;
            if (v) {
                float cntf = (float)(unsigned int)(v >> 57);
                float rcp = 16383.0f / cntf;
                unsigned int sx = (unsigned int)(v & 0x3FFFFULL);
                unsigned int sy = (unsigned int)((v >> 18) & 0x3FFFFULL);
                unsigned int sz = (unsigned int)((v >> 36) & 0x1FFFFFULL);
                u64 mqx = (u64)(unsigned int)rintf((float)sx * rcp * 2.44140625e-4f);
                u64 mqy = (u64)(unsigned int)rintf((float)sy * rcp * 2.44140625e-4f);
                u64 mqz = (u64)(unsigned int)rintf((float)sz * rcp * 3.0517578125e-5f);
                int lr = wrank[s >> 6] +
                         __popcll(msk[s >> 6] & ((1ULL << (s & 63)) - 1ULL));
                outv = mqx | (mqy << 14) | (mqz << 28) | ((u64)lr << 42);
            }
            pk[base + s] = outv;
        }
    }
}

// 1 block, 512 threads: gbase[401] = exclusive prefix of bcnt; gbase[400]=nu;
// grid-size output.
__global__ void scan_bcnt_kernel(const int* __restrict__ bcnt,
                                 int* __restrict__ gbase,
                                 float* __restrict__ gs) {
    __shared__ int wsum[8];
    int tid = threadIdx.x;          // 0..511
    int lane = tid & 63;
    int wv = tid >> 6;              // 0..7
    int v = (tid < NBUCK) ? bcnt[tid] : 0;
    int x = v;
#pragma unroll
    for (int off = 1; off < 64; off <<= 1) {
        int y = __shfl_up(x, off, 64);
        if (lane >= off) x += y;
    }
    if (lane == 63) wsum[wv] = x;
    __syncthreads();
    if (wv == 0) {
        int w = (lane < 8) ? wsum[lane] : 0;
#pragma unroll
        for (int off = 1; off < 8; off <<= 1) {
            int y = __shfl_up(w, off, 64);
            if (lane >= off) w += y;
        }
        if (lane < 8) wsum[lane] = w;   // inclusive wave prefix
    }
    __syncthreads();
    int waveExcl = (wv == 0) ? 0 : wsum[wv - 1];
    if (tid < NBUCK) gbase[tid] = waveExcl + x - v;
    if (tid == 511) gbase[NBUCK] = waveExcl + x;   // total = num_unique
    if (tid == 0) { gs[0] = 400.0f; gs[1] = 400.0f; gs[2] = 1.0f; }
}

__device__ __forceinline__ void point_feat(float bfl, float x, float y, float z,
                                           float inten, float t,
                                           const u64* __restrict__ pk,
                                           const int* __restrict__ gbase,
                                           float* f, float* r) {
    float u = (x + 50.0f) * 4.0f;
    float v = (y + 50.0f) * 4.0f;
    int cx = (int)u;
    int cy = (int)v;
    int key = (((int)bfl * GX + cx) * GY + cy) * NT + (int)t;
    u64 m = pk[key];                   // [mqx|mqy|mqz|local rank]
    int bb = gbase[key / TILE];        // 1.6KB table, L1-resident
    const float qs = 1.0f / 16383.0f;
    float mdx = (float)(unsigned int)(m & 0x3FFFULL) * qs;
    float mdy = (float)(unsigned int)((m >> 14) & 0x3FFFULL) * qs;
    float mdz = (float)(unsigned int)((m >> 28) & 0x3FFFULL) * qs;
    float bx = (float)cx * 0.25f - 50.0f;
    float by = (float)cy * 0.25f - 50.0f;
    f[0] = x;
    f[1] = y;
    f[2] = z;
    f[3] = inten;
    f[4] = x - (bx + mdx * 0.25f);
    f[5] = y - (by + mdy * 0.25f);
    f[6] = z - (-5.0f + mdz * 8.0f);
    f[7] = x - (bx + 0.125f);
    f[8] = y - (by + 0.125f);
    *r = (float)((unsigned int)(m >> 42) + bb);
}

// Final kernel: OUT-ROLE FIRST (bid < nb_out) — R1-proven 4pt body with
// self-padding of unq rows >= nu; unq-role moved to 400 TAIL blocks.
__global__ void out_fused_kernel(const vf4* __restrict__ pts4, int n,
                                 int nb_out,
                                 const u64* __restrict__ pk,
                                 const int* __restrict__ gbase,
                                 const u64* __restrict__ gmask,
                                 float* __restrict__ feat,
                                 vf4* __restrict__ uinv4,
                                 vf4* __restrict__ unq4) {
    int bid = blockIdx.x;
    int tid = threadIdx.x;

    if (bid < nb_out) {
        // ---- out-role: 4 points / thread (R1-proven body + self-pad) ----
        int i = bid * 256 + tid;
        int p0 = i * 4;
        if (p0 >= n) return;
        int nu = gbase[NBUCK];
        if (p0 + 3 < n) {
            vf4 a0 = __builtin_nontemporal_load(pts4 + (size_t)6 * i + 0);
            vf4 a1 = __builtin_nontemporal_load(pts4 + (size_t)6 * i + 1);
            vf4 a2 = __builtin_nontemporal_load(pts4 + (size_t)6 * i + 2);
            vf4 a3 = __builtin_nontemporal_load(pts4 + (size_t)6 * i + 3);
            vf4 a4 = __builtin_nontemporal_load(pts4 + (size_t)6 * i + 4);
            vf4 a5 = __builtin_nontemporal_load(pts4 + (size_t)6 * i + 5);
            float f[36];
            float r[4];
            point_feat(a0.x, a0.y, a0.z, a0.w, a1.x, a1.y, pk, gbase, f + 0, r + 0);
            point_feat(a1.z, a1.w, a2.x, a2.y, a2.z, a2.w, pk, gbase, f + 9, r + 1);
            point_feat(a3.x, a3.y, a3.z, a3.w, a4.x, a4.y, pk, gbase, f + 18, r + 2);
            point_feat(a4.z, a4.w, a5.x, a5.y, a5.z, a5.w, pk, gbase, f + 27, r + 3);
            vf4* dst = (vf4*)(feat + (size_t)i * 36);  // 144B/thread, aligned
#pragma unroll
            for (int k = 0; k < 9; ++k) {
                vf4 o = {f[4 * k], f[4 * k + 1], f[4 * k + 2], f[4 * k + 3]};
                dst[k] = o;
            }
            vf4 rv = {r[0], r[1], r[2], r[3]};
            uinv4[i] = rv;
#pragma unroll
            for (int k = 0; k < 4; ++k) {
                int row = p0 + k;
                if (row >= nu) {
                    vf4 neg = {-1.0f, -1.0f, -1.0f, -1.0f};
                    unq4[row] = neg;
                }
            }
        } else {
            const float* p = (const float*)pts4;
            float* uinv = (float*)uinv4;
            for (int j = p0; j < n; ++j) {
                float f[9];
                float r;
                point_feat(p[6 * j], p[6 * j + 1], p[6 * j + 2], p[6 * j + 3],
                           p[6 * j + 4], p[6 * j + 5], pk, gbase, f, &r);
                for (int k = 0; k < 9; ++k) feat[(size_t)j * 9 + k] = f[k];
                uinv[j] = r;
                if (j >= nu) {
                    vf4 neg = {-1.0f, -1.0f, -1.0f, -1.0f};
                    unq4[j] = neg;
                }
            }
        }
        return;
    }

    // ---- unq-role: tail blocks, one per bucket ----
    int ub = bid - nb_out;           // 0..NBUCK-1
    __shared__ u64 mw[NWORDS];
    __shared__ int w0tot;
    int lane = tid & 63;
    if (tid < NWORDS) mw[tid] = gmask[(size_t)ub * NWORDS + tid];
    __syncthreads();
    int pc = 0, xi = 0;
    if (tid < NWORDS) {
        pc = __popcll(mw[tid]);
        xi = pc;
#pragma unroll
        for (int off = 1; off < 64; off <<= 1) {
            int y = __shfl_up(xi, off, 64);
            if (lane >= off) xi += y;
        }
        if (tid == 63) w0tot = xi;
    }
    __syncthreads();
    if (tid < NWORDS) {
        int r = gbase[ub] + xi - pc + ((tid >= 64) ? w0tot : 0);
        u64 w = mw[tid];
        int keyb = ub * TILE + tid * 64;
        while (w) {
            int bit = __builtin_ctzll(w);
            w &= w - 1;
            int k = keyb + bit;
            int tt = k % NT;
            int k2 = k / NT;
            int yy = k2 % GY;
            int k3 = k2 / GY;
            int xx = k3 % GX;
            int bb = k3 / GX;
            vf4 row = {(float)bb, (float)tt, (float)yy, (float)xx};
            unq4[r] = row;
            ++r;
        }
    }
}

extern "C" void kernel_launch(void* const* d_in, const int* in_sizes, int n_in,
                              void* d_out, int out_size, void* d_ws, size_t ws_size,
                              hipStream_t stream) {
    const float* pts = (const float*)d_in[0];
    int n = in_sizes[0] / 6;       // 2,000,000

    char* ws = (char*)d_ws;
    u64* pk = (u64*)ws;                                  // NKEYS*8 = 25.6 MB
    int* gcnt  = (int*)(ws + (size_t)NKEYS * 8);         // 400 ints
    int* bcnt  = (int*)(ws + (size_t)NKEYS * 8 + 2048);
    int* gbase = (int*)(ws + (size_t)NKEYS * 8 + 4096);  // 401 ints
    u64* gmask = (u64*)(ws + (size_t)NKEYS * 8 + 8192);  // 400*128*8 = 410KB

    float* feat = (float*)d_out;             // (n, 9)
    float* unq  = feat + (size_t)n * 9;      // (n, 4)
    float* uinv = feat + (size_t)n * 13;     // (n,)
    float* gs   = feat + (size_t)n * 14;     // (3,)

    // Records scratch (400*5632*8B = 18MB) aliases the feat region; feat is
    // only written by out_fused after bucket_accum consumed the records.
    u64* recs = (u64*)d_out;

    (void)hipMemsetAsync(gcnt, 0, NBUCK * sizeof(int), stream);

    int nb_bin = (n + BINPTS - 1) / BINPTS;              // 489
    bin_kernel<<<nb_bin, 1024, 0, stream>>>((const vf4*)pts, n, gcnt, recs);
    bucket_accum_kernel<<<NBUCK, 1024, 0, stream>>>(recs, gcnt, pk, bcnt, gmask);
    scan_bcnt_kernel<<<1, 512, 0, stream>>>(bcnt, gbase, gs);

    int nq = (n + 3) / 4;
    int nb_out = (nq + 255) / 256;                       // 1954
    out_fused_kernel<<<nb_out + NBUCK, 256, 0, stream>>>(
        (const vf4*)pts, n, nb_out, pk, gbase, gmask, feat, (vf4*)uinv,
        (vf4*)unq);
}